// Round 14
// baseline (925.303 us; speedup 1.0000x reference)
//
#include <hip/hip_runtime.h>
#include <math.h>

constexpr int B = 64;
constexpr int L = 4096;
constexpr int C = 256;
constexpr int H = 32;

constexpr int NBLK = 1024;        // 4 blocks/CU x 256 CU — co-resident by launch_bounds
constexpr int SEGS = NBLK / B;    // 16 segments per batch
constexpr int SROWS = L / SEGS;   // 256 rows per segment (256 KB)

typedef float v4f __attribute__((ext_vector_type(4)));

// Device-scope software grid barrier. Arrival = one RMW (release). Spin =
// acquire LOADS (non-serializing; R13 proved RMW-spin costs ~300 µs).
// Co-residency: __launch_bounds__(256,4) -> 4 blocks/CU x 256 CU = 1024 = grid.
__device__ __forceinline__ void grid_barrier(unsigned int* cnt, unsigned int target) {
    __syncthreads();
    if (threadIdx.x == 0) {
        __threadfence();  // release prior global writes (cross-XCD writeback)
        __hip_atomic_fetch_add(cnt, 1u, __ATOMIC_RELEASE, __HIP_MEMORY_SCOPE_AGENT);
        while (__hip_atomic_load(cnt, __ATOMIC_ACQUIRE, __HIP_MEMORY_SCOPE_AGENT) < target) {
            __builtin_amdgcn_s_sleep(8);
        }
    }
    __syncthreads();
    __threadfence();      // acquire: discard stale cached lines
}

__global__ __launch_bounds__(256, 4) void se_fused(
        const float* __restrict__ in,
        const float* __restrict__ w1, const float* __restrict__ b1,
        const float* __restrict__ w2, const float* __restrict__ b2,
        v4f* __restrict__ out,
        float* __restrict__ partial, float* __restrict__ g,
        unsigned int* __restrict__ bar) {
    const int j = blockIdx.x;
    const int b = j >> 4;        // j / SEGS
    const int seg = j & 15;      // j % SEGS
    const int t = threadIdx.x;
    const int c4 = t & 63;
    const int r0 = t >> 6;       // 0..3

    const v4f* base = reinterpret_cast<const v4f*>(in)
                    + (size_t)b * L * (C / 4) + (size_t)seg * SROWS * (C / 4);

    // ---- Phase 1: reduce this block's 256 rows (plain loads -> MALL-warm) ----
    v4f acc = (v4f)(0.f);
    #pragma unroll
    for (int grp = 0; grp < 8; ++grp) {
        const size_t i0 = (size_t)(r0 + grp * 32) * (C / 4) + c4;
        v4f v[8];
        #pragma unroll
        for (int k = 0; k < 8; ++k) v[k] = base[i0 + (size_t)k * 4 * (C / 4)];
        #pragma unroll
        for (int k = 0; k < 8; ++k) acc += v[k];
    }
    __shared__ v4f red[4][C / 4];
    red[r0][c4] = acc;
    __syncthreads();
    if (r0 == 0) {
        v4f s = red[0][c4] + red[1][c4] + red[2][c4] + red[3][c4];
        reinterpret_cast<v4f*>(partial + (size_t)j * C)[c4] = s;
    }

    grid_barrier(&bar[0], NBLK);

    // ---- Phase 2: blocks 0..63 compute the gate row for batch = j ----
    if (j < B) {
        __shared__ float sm[C];
        __shared__ float ep[8][H];
        __shared__ float em[H];

        float a = 0.f;
        const float* p = partial + (size_t)j * SEGS * C + t;
        #pragma unroll
        for (int k = 0; k < SEGS; ++k) a += p[(size_t)k * C];
        sm[t] = a * (1.0f / (float)L);
        __syncthreads();

        {   // w1: all 256 threads — thread t does h = t&31 over a 32-c slice
            const int h = t & 31, cs = t >> 5;
            float a1 = 0.f;
            #pragma unroll 8
            for (int c = cs * 32; c < cs * 32 + 32; ++c) a1 += sm[c] * w1[c * H + h];
            ep[cs][h] = a1;
        }
        __syncthreads();
        if (t < H) {
            float a1 = b1[t];
            #pragma unroll
            for (int k = 0; k < 8; ++k) a1 += ep[k][t];
            em[t] = fmaxf(a1, 0.0f);
        }
        __syncthreads();

        float a2 = b2[t];
        #pragma unroll
        for (int h = 0; h < H; ++h) a2 += em[h] * w2[h * C + t];
        g[j * C + t] = 1.0f / (1.0f + expf(-a2));
    }

    grid_barrier(&bar[1], NBLK);

    // ---- Phase 3: scale this block's rows (nt loads + nt stores, 8-deep) ----
    const v4f gv = reinterpret_cast<const v4f*>(g)[b * (C / 4) + c4];
    v4f* outb = out + (size_t)b * L * (C / 4) + (size_t)seg * SROWS * (C / 4);

    #pragma unroll
    for (int grp = 0; grp < 8; ++grp) {
        const size_t i0 = (size_t)(r0 + grp * 32) * (C / 4) + c4;
        v4f v[8];
        #pragma unroll
        for (int k = 0; k < 8; ++k)
            v[k] = __builtin_nontemporal_load(&base[i0 + (size_t)k * 4 * (C / 4)]);
        #pragma unroll
        for (int k = 0; k < 8; ++k)
            __builtin_nontemporal_store(v[k] * gv, &outb[i0 + (size_t)k * 4 * (C / 4)]);
    }
}

extern "C" void kernel_launch(void* const* d_in, const int* in_sizes, int n_in,
                              void* d_out, int out_size, void* d_ws, size_t ws_size,
                              hipStream_t stream) {
    const float* in = (const float*)d_in[0];
    const float* w1 = (const float*)d_in[1];
    const float* b1 = (const float*)d_in[2];
    const float* w2 = (const float*)d_in[3];
    const float* b2 = (const float*)d_in[4];
    v4f* out = (v4f*)d_out;

    float* partial = (float*)d_ws;                   // NBLK*C floats = 1 MB
    float* g = partial + (size_t)NBLK * C;           // B*C floats = 64 KB
    unsigned int* bar = (unsigned int*)(g + B * C);  // 2 counters

    hipMemsetAsync(bar, 0, 2 * sizeof(unsigned int), stream);
    se_fused<<<NBLK, 256, 0, stream>>>(in, w1, b1, w2, b2, out, partial, g, bar);
}

// Round 15
// 228.772 us; speedup vs baseline: 4.0446x; 4.0446x over previous
//
#include <hip/hip_runtime.h>
#include <math.h>

constexpr int B = 64;
constexpr int L = 4096;
constexpr int C = 256;
constexpr int H = 32;

constexpr int NCH = 32;          // chunks per batch
constexpr int ROWS = L / NCH;    // 128 rows per chunk (128 KB)

typedef float v4f __attribute__((ext_vector_type(4)));

// ---------------- Pass 1: reduce + last-arriver computes the gate ----------------
// grid = B*NCH = 2048 blocks, 256 threads. Streaming part identical to R9
// (plain loads -> input allocates into MALL for pass 2's nt re-read).
// After writing its partial, each block atomicAdd's a per-batch counter;
// the 32nd arriver for batch b folds the partials (agent-scope loads bypass
// the stale per-XCD L2) and computes the gate row. No waiting anywhere.
// Counter is NEVER reset: modulo-32 test makes it replay-safe (each call
// adds exactly 32 per batch), so no memset node is needed.
__global__ __launch_bounds__(256) void se_reduce_gate(
        const float* __restrict__ in,
        const float* __restrict__ w1, const float* __restrict__ b1,
        const float* __restrict__ w2, const float* __restrict__ b2,
        float* __restrict__ partial, float* __restrict__ g,
        unsigned int* __restrict__ cnt) {
    const int b = blockIdx.x / NCH;
    const int chunk = blockIdx.x % NCH;
    const int t = threadIdx.x;
    const int c4 = t & 63;
    const int r0 = t >> 6;

    const v4f* base = reinterpret_cast<const v4f*>(
        in + (size_t)b * L * C + (size_t)chunk * ROWS * C);

    v4f acc = (v4f)(0.f);
    #pragma unroll
    for (int grp = 0; grp < 4; ++grp) {
        const size_t i0 = (size_t)(r0 + grp * 32) * (C / 4) + c4;
        v4f v[8];
        #pragma unroll
        for (int j = 0; j < 8; ++j)
            v[j] = base[i0 + (size_t)j * 4 * (C / 4)];
        #pragma unroll
        for (int j = 0; j < 8; ++j)
            acc += v[j];
    }

    __shared__ v4f red[4][C / 4];
    red[r0][c4] = acc;
    __syncthreads();
    if (r0 == 0) {
        v4f s = red[0][c4] + red[1][c4] + red[2][c4] + red[3][c4];
        reinterpret_cast<v4f*>(partial + (size_t)blockIdx.x * C)[c4] = s;
    }

    // ---- arrival: am I the last block of batch b? ----
    __shared__ int is_last;
    __syncthreads();
    if (t == 0) {
        __threadfence();  // agent release: write back this XCD's dirty partials
        unsigned int old = atomicAdd(&cnt[b], 1u);
        is_last = ((old & 31u) == 31u) ? 1 : 0;
    }
    __syncthreads();
    if (!is_last) return;

    // ---- last arriver: fold 32 partials + tiny gate MLP ----
    __shared__ float sm[C];
    __shared__ float em[H];

    {
        float a = 0.f;
        const float* p = partial + (size_t)b * NCH * C + t;
        #pragma unroll
        for (int k = 0; k < NCH; ++k)
            // agent-scope relaxed load: bypasses (possibly stale) own-XCD L2
            a += __hip_atomic_load(&p[(size_t)k * C], __ATOMIC_RELAXED,
                                   __HIP_MEMORY_SCOPE_AGENT);
        sm[t] = a * (1.0f / (float)L);
    }
    __syncthreads();

    if (t < H) {
        float a1 = b1[t];
        #pragma unroll 8
        for (int c = 0; c < C; ++c) a1 += sm[c] * w1[c * H + t];
        em[t] = fmaxf(a1, 0.0f);
    }
    __syncthreads();

    float a2 = b2[t];
    #pragma unroll
    for (int h = 0; h < H; ++h) a2 += em[h] * w2[h * C + t];
    g[b * C + t] = 1.0f / (1.0f + expf(-a2));
}

// ---------------- Pass 2: broadcast scale (identical to R9) ----------------
__global__ __launch_bounds__(256) void se_scale(const v4f* __restrict__ in,
                                                const float* __restrict__ g,
                                                v4f* __restrict__ out) {
    const int b = blockIdx.x / NCH;
    const int chunk = blockIdx.x % NCH;
    const int t = threadIdx.x;
    const int c4 = t & 63;
    const int r0 = t >> 6;  // 0..3

    const size_t base = (size_t)b * L * (C / 4)
                      + (size_t)chunk * ROWS * (C / 4) + c4;
    const v4f gv = reinterpret_cast<const v4f*>(g)[b * (C / 4) + c4];

    #pragma unroll
    for (int grp = 0; grp < 4; ++grp) {
        const size_t i0 = base + (size_t)(r0 + grp * 32) * (C / 4);
        v4f v[8];
        #pragma unroll
        for (int j = 0; j < 8; ++j)
            v[j] = __builtin_nontemporal_load(&in[i0 + (size_t)j * 4 * (C / 4)]);
        #pragma unroll
        for (int j = 0; j < 8; ++j)
            __builtin_nontemporal_store(v[j] * gv, &out[i0 + (size_t)j * 4 * (C / 4)]);
    }
}

extern "C" void kernel_launch(void* const* d_in, const int* in_sizes, int n_in,
                              void* d_out, int out_size, void* d_ws, size_t ws_size,
                              hipStream_t stream) {
    const float* in = (const float*)d_in[0];
    const float* w1 = (const float*)d_in[1];
    const float* b1 = (const float*)d_in[2];
    const float* w2 = (const float*)d_in[3];
    const float* b2 = (const float*)d_in[4];
    float* out = (float*)d_out;

    float* partial = (float*)d_ws;                   // B*NCH*C floats = 2 MB
    float* g = partial + (size_t)B * NCH * C;        // B*C floats = 64 KB
    unsigned int* cnt = (unsigned int*)(g + B * C);  // B counters, never reset
                                                     // (modulo-32 arrival test)

    se_reduce_gate<<<B * NCH, 256, 0, stream>>>(in, w1, b1, w2, b2,
                                                partial, g, cnt);
    se_scale<<<B * NCH, 256, 0, stream>>>(
        reinterpret_cast<const v4f*>(in), g, reinterpret_cast<v4f*>(out));
}

// Round 17
// 137.296 us; speedup vs baseline: 6.7395x; 1.6663x over previous
//
#include <hip/hip_runtime.h>
#include <math.h>

constexpr int B = 64;
constexpr int L = 4096;
constexpr int C = 256;
constexpr int H = 32;

constexpr int NCH = 32;          // chunks per batch
constexpr int ROWS = L / NCH;    // 128 rows per chunk (128 KB)

typedef float v4f __attribute__((ext_vector_type(4)));

// ---------------- Pass 1: per-(batch,chunk) column sums ----------------
// grid = B*NCH = 2048 blocks, 256 threads. PLAIN loads (allocate the input
// into L3 so pass 3's nt re-read hits — R8 proved nt loads here cost 6 µs).
// 8-deep explicit load batches for ILP.
__global__ __launch_bounds__(256) void se_reduce(const float* __restrict__ in,
                                                 float* __restrict__ partial) {
    const int b = blockIdx.x / NCH;
    const int chunk = blockIdx.x % NCH;
    const int t = threadIdx.x;
    const int c4 = t & 63;
    const int r0 = t >> 6;

    const v4f* base = reinterpret_cast<const v4f*>(
        in + (size_t)b * L * C + (size_t)chunk * ROWS * C);

    v4f acc = (v4f)(0.f);
    #pragma unroll
    for (int grp = 0; grp < 4; ++grp) {
        const size_t i0 = (size_t)(r0 + grp * 32) * (C / 4) + c4;
        v4f v[8];
        #pragma unroll
        for (int j = 0; j < 8; ++j)
            v[j] = base[i0 + (size_t)j * 4 * (C / 4)];
        #pragma unroll
        for (int j = 0; j < 8; ++j)
            acc += v[j];
    }

    __shared__ v4f red[4][C / 4];
    red[r0][c4] = acc;
    __syncthreads();
    if (r0 == 0) {
        v4f s = red[0][c4] + red[1][c4] + red[2][c4] + red[3][c4];
        reinterpret_cast<v4f*>(partial + (size_t)blockIdx.x * C)[c4] = s;
    }
}

// ---------------- Pass 2: fold partials + tiny gate MLP ----------------
// grid = B, block = 256. Separate dispatch: measured cheaper than fusing
// into the reduce (R10/R15) or any in-kernel grid sync (R13/R14).
__global__ __launch_bounds__(256) void se_gate(const float* __restrict__ partial,
                                               const float* __restrict__ w1,
                                               const float* __restrict__ b1,
                                               const float* __restrict__ w2,
                                               const float* __restrict__ b2,
                                               float* __restrict__ g) {
    const int b = blockIdx.x;
    const int t = threadIdx.x;

    __shared__ float sm[C];
    __shared__ float em[H];

    float acc = 0.f;
    const float* p = partial + (size_t)b * NCH * C + t;
    #pragma unroll 8
    for (int k = 0; k < NCH; ++k) acc += p[(size_t)k * C];
    sm[t] = acc * (1.0f / (float)L);
    __syncthreads();

    if (t < H) {
        float a1 = b1[t];
        #pragma unroll 8
        for (int c = 0; c < C; ++c) a1 += sm[c] * w1[c * H + t];
        em[t] = fmaxf(a1, 0.0f);
    }
    __syncthreads();

    float a2 = b2[t];
    #pragma unroll
    for (int h = 0; h < H; ++h) a2 += em[h] * w2[h * C + t];
    g[b * C + t] = 1.0f / (1.0f + expf(-a2));
}

// ---------------- Pass 3: broadcast scale ----------------
// nt loads (consume MALL-resident input without re-allocating/polluting) +
// nt stores (write stream bypasses cache; +26 µs vs plain, R6), 8-deep.
__global__ __launch_bounds__(256) void se_scale(const v4f* __restrict__ in,
                                                const float* __restrict__ g,
                                                v4f* __restrict__ out) {
    const int b = blockIdx.x / NCH;
    const int chunk = blockIdx.x % NCH;
    const int t = threadIdx.x;
    const int c4 = t & 63;
    const int r0 = t >> 6;  // 0..3

    const size_t base = (size_t)b * L * (C / 4)
                      + (size_t)chunk * ROWS * (C / 4) + c4;
    const v4f gv = reinterpret_cast<const v4f*>(g)[b * (C / 4) + c4];

    #pragma unroll
    for (int grp = 0; grp < 4; ++grp) {
        const size_t i0 = base + (size_t)(r0 + grp * 32) * (C / 4);
        v4f v[8];
        #pragma unroll
        for (int j = 0; j < 8; ++j)
            v[j] = __builtin_nontemporal_load(&in[i0 + (size_t)j * 4 * (C / 4)]);
        #pragma unroll
        for (int j = 0; j < 8; ++j)
            __builtin_nontemporal_store(v[j] * gv, &out[i0 + (size_t)j * 4 * (C / 4)]);
    }
}

extern "C" void kernel_launch(void* const* d_in, const int* in_sizes, int n_in,
                              void* d_out, int out_size, void* d_ws, size_t ws_size,
                              hipStream_t stream) {
    const float* in = (const float*)d_in[0];
    const float* w1 = (const float*)d_in[1];
    const float* b1 = (const float*)d_in[2];
    const float* w2 = (const float*)d_in[3];
    const float* b2 = (const float*)d_in[4];
    float* out = (float*)d_out;

    float* partial = (float*)d_ws;               // B*NCH*C floats = 2 MB
    float* g = partial + (size_t)B * NCH * C;    // B*C floats = 64 KB

    se_reduce<<<B * NCH, 256, 0, stream>>>(in, partial);
    se_gate<<<B, 256, 0, stream>>>(partial, w1, b1, w2, b2, g);
    se_scale<<<B * NCH, 256, 0, stream>>>(
        reinterpret_cast<const v4f*>(in), g, reinterpret_cast<v4f*>(out));
}